// Round 1
// 600.316 us; speedup vs baseline: 1.0704x; 1.0704x over previous
//
#include <hip/hip_runtime.h>
#include <hip/hip_bf16.h>

// Problem constants
#define NN   2048
#define DD   64
#define HH1  512
#define HH2  512
#define PP   2048
#define EE   16
#define KBIG (EE * HH2)   // 8192: concatenated expert K for the combine GEMM
#define SPLITS 2          // split-K for the big GEMM (partials alias dead h1)

typedef unsigned short ushort_t;
typedef __attribute__((ext_vector_type(8))) short bf16x8;
typedef __attribute__((ext_vector_type(4))) float f32x4;

__device__ __forceinline__ float b2f(ushort_t u) {
  union { unsigned int i; float f; } v; v.i = ((unsigned int)u) << 16; return v.f;
}
__device__ __forceinline__ ushort_t f2b(float f) {
  union { float f; unsigned int i; } v; v.f = f;
  unsigned int x = v.i;
  unsigned int r = (x + 0x7fffu + ((x >> 16) & 1u)) >> 16;
  return (ushort_t)r;
}
// dtype-aware scalar load: isb ? bf16[i] : fp32[i]
__device__ __forceinline__ float ldf(const void* p, size_t i, int isb) {
  return isb ? b2f(((const ushort_t*)p)[i]) : ((const float*)p)[i];
}

__device__ __forceinline__ void async16(ushort_t* lds, const ushort_t* g) {
  __builtin_amdgcn_global_load_lds(
      (const __attribute__((address_space(1))) void*)g,
      (__attribute__((address_space(3))) void*)lds, 16, 0, 0);
}

// ---------------------------------------------------------------------------
// Dtype sniffer: bf16 buffer -> low 16 bits of each u32 are a valid N(0,1)
// bf16 (exp in [110,135] ~99.9%); fp32 -> those bits are mantissa noise (~10%).
// ---------------------------------------------------------------------------
__global__ void k_sniff(const unsigned int* __restrict__ zraw,
                        int* __restrict__ flag) {
  __shared__ int cnt[256];
  int t = threadIdx.x;
  int c = 0;
  for (int i = t; i < 1024; i += 256) {
    unsigned int u = zraw[i];
    unsigned int e = (u >> 7) & 0xFFu;
    c += (e >= 110u && e <= 135u) ? 1 : 0;
  }
  cnt[t] = c;
  __syncthreads();
  for (int s = 128; s > 0; s >>= 1) {
    if (t < s) cnt[t] += cnt[t + s];
    __syncthreads();
  }
  if (t == 0) *flag = (cnt[0] >= 512) ? 1 : 0;
}

// ---------------------------------------------------------------------------
// MFMA C/D-layout probe: one wave, asymmetric integer A,B (exact in bf16).
// Checks interp0 (m=quad*4+r, n=lane&15) vs interp1 (swapped). mapflag=0/1.
// ---------------------------------------------------------------------------
__global__ void k_probe(int* __restrict__ mapflag) {
  __shared__ ushort_t Ap[16 * 32];
  __shared__ ushort_t Bp[16 * 32];
  int t = threadIdx.x;  // 64 threads
  for (int i = t; i < 512; i += 64) {
    int r = i >> 5, k = i & 31;
    Ap[i] = f2b((float)((r + k) % 7));
    Bp[i] = f2b((float)((2 * r + k) % 5));
  }
  __syncthreads();
  int lr = t & 15, quad = t >> 4;
  bf16x8 a = *(const bf16x8*)&Ap[lr * 32 + quad * 8];
  bf16x8 b = *(const bf16x8*)&Bp[lr * 32 + quad * 8];
  f32x4 acc = {};
  acc = __builtin_amdgcn_mfma_f32_16x16x32_bf16(a, b, acc, 0, 0, 0);
  bool m0 = true, m1 = true;
  for (int r = 0; r < 4; ++r) {
    float r0 = 0.f, r1 = 0.f;
    for (int k = 0; k < 32; ++k) {
      r0 += (float)(((quad * 4 + r) + k) % 7) * (float)((2 * lr + k) % 5);
      r1 += (float)((lr + k) % 7) * (float)((2 * (quad * 4 + r) + k) % 5);
    }
    m0 &= fabsf(acc[r] - r0) < 0.5f;
    m1 &= fabsf(acc[r] - r1) < 0.5f;
  }
  unsigned long long b0 = __ballot(m0);
  unsigned long long b1 = __ballot(m1);
  if (t == 0) *mapflag = (b0 == ~0ULL) ? 0 : ((b1 == ~0ULL) ? 1 : 0);
}

// ---------------------------------------------------------------------------
// Convert input buffer (bf16 or fp32 per flag) to canonical bf16.
// ---------------------------------------------------------------------------
__global__ void k_convert(const void* __restrict__ src,
                          ushort_t* __restrict__ dst, int n,
                          const int* __restrict__ flag) {
  int isb = *flag;
  int stride = gridDim.x * blockDim.x;
  for (int g = blockIdx.x * blockDim.x + threadIdx.x; g * 8 < n; g += stride) {
    int base = g * 8;
    ushort_t ov[8];
    if (isb) {
      *(uint4*)ov = *(const uint4*)((const ushort_t*)src + base);
    } else {
      const float* s = (const float*)src + base;
      float4 f0 = *(const float4*)s;
      float4 f1 = *(const float4*)(s + 4);
      ov[0] = f2b(f0.x); ov[1] = f2b(f0.y); ov[2] = f2b(f0.z); ov[3] = f2b(f0.w);
      ov[4] = f2b(f1.x); ov[5] = f2b(f1.y); ov[6] = f2b(f1.z); ov[7] = f2b(f1.w);
    }
    *(uint4*)(dst + base) = *(uint4*)ov;
  }
}

// ---------------------------------------------------------------------------
// Transpose + convert per-expert weight [K][H] -> bf16, 64x64 tiles.
// Generalized dst: dst += e*e_dst_off; row h stored at row-stride ld_dst.
// Optional Amask: scale row h of expert e by A[h,e] (binary -> exact in bf16).
// ---------------------------------------------------------------------------
__global__ void k_transpose_cvt(const void* __restrict__ src_,
                                ushort_t* __restrict__ dst, int K, int H,
                                int ld_dst, long e_dst_off,
                                const void* __restrict__ Amask,
                                const int* __restrict__ flag) {
  __shared__ ushort_t tile[64][68];
  int isb = *flag;
  int e = blockIdx.z;
  size_t ebase = (size_t)e * K * H;
  dst += (size_t)e * e_dst_off;
  int h0 = blockIdx.x * 64, k0 = blockIdx.y * 64;
  int t = threadIdx.x;
#pragma unroll
  for (int it = 0; it < 2; ++it) {
    int c = it * 256 + t;
    int row = c >> 3, col = (c & 7) * 8;
    size_t idx = ebase + (size_t)(k0 + row) * H + h0 + col;
    ushort_t tmp[8];
    if (isb) {
      *(uint4*)tmp = *(const uint4*)((const ushort_t*)src_ + idx);
    } else {
      const float* s = (const float*)src_ + idx;
      float4 f0 = *(const float4*)s;
      float4 f1 = *(const float4*)(s + 4);
      tmp[0] = f2b(f0.x); tmp[1] = f2b(f0.y); tmp[2] = f2b(f0.z); tmp[3] = f2b(f0.w);
      tmp[4] = f2b(f1.x); tmp[5] = f2b(f1.y); tmp[6] = f2b(f1.z); tmp[7] = f2b(f1.w);
    }
#pragma unroll
    for (int j = 0; j < 8; ++j) tile[row][col + j] = tmp[j];
  }
  __syncthreads();
#pragma unroll
  for (int it = 0; it < 2; ++it) {
    int c = it * 256 + t;
    int row = c >> 3, col = (c & 7) * 8;
    ushort_t tmp[8];
#pragma unroll
    for (int j = 0; j < 8; ++j) tmp[j] = tile[col + j][row];
    if (Amask) {
      float a = ldf(Amask, (size_t)(h0 + row) * EE + e, isb);
#pragma unroll
      for (int j = 0; j < 8; ++j) tmp[j] = f2b(a * b2f(tmp[j]));
    }
    *(uint4*)(dst + (size_t)(h0 + row) * ld_dst + k0 + col) = *(uint4*)tmp;
  }
}

// ---------------------------------------------------------------------------
// Gate: reads RAW inputs (dtype per flag) in fp32 — exact gate path.
// ---------------------------------------------------------------------------
__global__ void k_gate(const void* __restrict__ z,
                       const void* __restrict__ Wg1,
                       const void* __restrict__ bg1,
                       const void* __restrict__ Wg2,
                       const void* __restrict__ bg2,
                       const int* __restrict__ flag,
                       float* __restrict__ gate) {
  __shared__ float sW1[64][65];
  __shared__ float sW2[64][16];
  __shared__ float sb1[64];
  __shared__ float sb2[16];
  __shared__ float sz[4][64];
  __shared__ float shid[4][64];
  __shared__ float sg[4][16];
  int isb = *flag;
  int t = threadIdx.x;
  for (int i = t; i < 64 * 64; i += 256) sW1[i >> 6][i & 63] = ldf(Wg1, i, isb);
  for (int i = t; i < 64 * 16; i += 256) sW2[i >> 4][i & 15] = ldf(Wg2, i, isb);
  if (t < 64) sb1[t] = ldf(bg1, t, isb);
  if (t < 16) sb2[t] = ldf(bg2, t, isb);
  int w = t >> 6, l = t & 63;
  int n = blockIdx.x * 4 + w;
  sz[w][l] = ldf(z, (size_t)n * DD + l, isb);
  __syncthreads();
  float acc = sb1[l];
#pragma unroll
  for (int d = 0; d < 64; ++d) acc += sz[w][d] * sW1[d][l];
  shid[w][l] = fmaxf(acc, 0.f);
  __syncthreads();
  if (l < 16) {
    float g = sb2[l];
#pragma unroll
    for (int j = 0; j < 64; ++j) g += shid[w][j] * sW2[j][l];
    sg[w][l] = g;
  }
  __syncthreads();
  if (l < 16) {
    float m = -1e30f;
    for (int e2 = 0; e2 < 16; ++e2) m = fmaxf(m, sg[w][e2]);
    float s = 0.f;
    for (int e2 = 0; e2 < 16; ++e2) s += __expf(sg[w][e2] - m);
    gate[(size_t)n * EE + l] = __expf(sg[w][l] - m) / s;
  }
}

// ---------------------------------------------------------------------------
// Batched GEMM: C[e][m][n] = relu( sum_k A[e][m][k]*BT[e][n][k] + bias[e][n] )
// optionally scaled by gs[m,e] (gate fold for layer 2). Stores bf16 at
// Cout[e*c_stride_e + m*ldc + n]. 128x128 tile, BK=32, 4 waves, mfma 16x16x32.
// ---------------------------------------------------------------------------
__global__ __launch_bounds__(256) void k_gemm_bt_relu(
    const ushort_t* __restrict__ Aact, const ushort_t* __restrict__ Bt,
    const ushort_t* __restrict__ bias, ushort_t* __restrict__ Cout,
    int M, int K, int ldc,
    long a_stride_e, long b_stride_e, long bias_stride_e, long c_stride_e,
    const float* __restrict__ gs,
    const int* __restrict__ mapflag) {
  __shared__ ushort_t As[128 * 32];
  __shared__ ushort_t Bs[128 * 32];
  int e = blockIdx.z;
  Aact += (size_t)e * a_stride_e;
  Bt   += (size_t)e * b_stride_e;
  bias += (size_t)e * bias_stride_e;
  Cout += (size_t)e * c_stride_e;
  int m0 = blockIdx.y * 128, n0 = blockIdx.x * 128;
  int t = threadIdx.x;
  int w = t >> 6, l = t & 63;
  int wm = (w >> 1) * 64, wn = (w & 1) * 64;
  int lr = l & 15, quad = l >> 4;
  int mf = *mapflag;

  f32x4 acc[4][4] = {};
  for (int k0 = 0; k0 < K; k0 += 32) {
#pragma unroll
    for (int it = 0; it < 2; ++it) {
      int c = it * 256 + t;
      int row = c >> 2, kk = (c & 3) * 8;
      async16(&As[row * 32 + kk], Aact + (size_t)(m0 + row) * K + k0 + kk);
    }
#pragma unroll
    for (int it = 0; it < 2; ++it) {
      int c = it * 256 + t;
      int row = c >> 2, kk = (c & 3) * 8;
      async16(&Bs[row * 32 + kk], Bt + (size_t)(n0 + row) * K + k0 + kk);
    }
    __syncthreads();
    bf16x8 af[4], bfr[4];
#pragma unroll
    for (int i = 0; i < 4; ++i)
      af[i] = *(const bf16x8*)&As[(wm + i * 16 + lr) * 32 + quad * 8];
#pragma unroll
    for (int j = 0; j < 4; ++j)
      bfr[j] = *(const bf16x8*)&Bs[(wn + j * 16 + lr) * 32 + quad * 8];
#pragma unroll
    for (int i = 0; i < 4; ++i)
#pragma unroll
      for (int j = 0; j < 4; ++j)
        acc[i][j] = __builtin_amdgcn_mfma_f32_16x16x32_bf16(af[i], bfr[j],
                                                            acc[i][j], 0, 0, 0);
    __syncthreads();
  }
  if (mf == 0) {
    float gv[4][4];
#pragma unroll
    for (int i = 0; i < 4; ++i)
#pragma unroll
      for (int r = 0; r < 4; ++r)
        gv[i][r] = gs ? gs[(size_t)(m0 + wm + i * 16 + quad * 4 + r) * EE + e]
                      : 1.f;
#pragma unroll
    for (int j = 0; j < 4; ++j) {
      int n = n0 + wn + j * 16 + lr;
      float bv = b2f(bias[n]);
#pragma unroll
      for (int i = 0; i < 4; ++i)
#pragma unroll
        for (int r = 0; r < 4; ++r) {
          int m = m0 + wm + i * 16 + quad * 4 + r;
          Cout[(size_t)m * ldc + n] =
              f2b(fmaxf(acc[i][j][r] + bv, 0.f) * gv[i][r]);
        }
    }
  } else {
#pragma unroll
    for (int i = 0; i < 4; ++i) {
      int m = m0 + wm + i * 16 + lr;
      float gvi = gs ? gs[(size_t)m * EE + e] : 1.f;
#pragma unroll
      for (int j = 0; j < 4; ++j)
#pragma unroll
        for (int r = 0; r < 4; ++r) {
          int n = n0 + wn + j * 16 + quad * 4 + r;
          Cout[(size_t)m * ldc + n] =
              f2b(fmaxf(acc[i][j][r] + b2f(bias[n]), 0.f) * gvi);
        }
    }
  }
}

// ---------------------------------------------------------------------------
// Big combine GEMM: numerator partials.
// part[s][n][p] = sum_{k in split s} H2big[n][k] * W3big[p][k], K = 8192.
// Split-K over blockIdx.z for occupancy (16x16 grid alone = 1 block/CU cliff).
// ---------------------------------------------------------------------------
__global__ __launch_bounds__(256) void k_bigk(
    const ushort_t* __restrict__ Ab,   // [N][KBIG] = gate-scaled h2
    const ushort_t* __restrict__ Bb,   // [P][KBIG] = A-masked W3^T
    float* __restrict__ part,          // [SPLITS][N][P] fp32
    const int* __restrict__ mapflag) {
  __shared__ ushort_t As[128 * 32];
  __shared__ ushort_t Bs[128 * 32];
  int s = blockIdx.z;
  int m0 = blockIdx.y * 128, n0 = blockIdx.x * 128;
  int t = threadIdx.x;
  int w = t >> 6, l = t & 63;
  int wm = (w >> 1) * 64, wn = (w & 1) * 64;
  int lr = l & 15, quad = l >> 4;
  int mf = *mapflag;
  float* out = part + (size_t)s * NN * PP;
  int kbeg = s * (KBIG / SPLITS), kend = kbeg + KBIG / SPLITS;

  f32x4 acc[4][4] = {};
  for (int k0 = kbeg; k0 < kend; k0 += 32) {
#pragma unroll
    for (int it = 0; it < 2; ++it) {
      int c = it * 256 + t;
      int row = c >> 2, kk = (c & 3) * 8;
      async16(&As[row * 32 + kk], Ab + (size_t)(m0 + row) * KBIG + k0 + kk);
    }
#pragma unroll
    for (int it = 0; it < 2; ++it) {
      int c = it * 256 + t;
      int row = c >> 2, kk = (c & 3) * 8;
      async16(&Bs[row * 32 + kk], Bb + (size_t)(n0 + row) * KBIG + k0 + kk);
    }
    __syncthreads();
    bf16x8 af[4], bfr[4];
#pragma unroll
    for (int i = 0; i < 4; ++i)
      af[i] = *(const bf16x8*)&As[(wm + i * 16 + lr) * 32 + quad * 8];
#pragma unroll
    for (int j = 0; j < 4; ++j)
      bfr[j] = *(const bf16x8*)&Bs[(wn + j * 16 + lr) * 32 + quad * 8];
#pragma unroll
    for (int i = 0; i < 4; ++i)
#pragma unroll
      for (int j = 0; j < 4; ++j)
        acc[i][j] = __builtin_amdgcn_mfma_f32_16x16x32_bf16(af[i], bfr[j],
                                                            acc[i][j], 0, 0, 0);
    __syncthreads();
  }
  if (mf == 0) {
#pragma unroll
    for (int j = 0; j < 4; ++j) {
      int n = n0 + wn + j * 16 + lr;
#pragma unroll
      for (int i = 0; i < 4; ++i)
#pragma unroll
        for (int r = 0; r < 4; ++r) {
          int m = m0 + wm + i * 16 + quad * 4 + r;
          out[(size_t)m * PP + n] = acc[i][j][r];
        }
    }
  } else {
#pragma unroll
    for (int i = 0; i < 4; ++i) {
      int m = m0 + wm + i * 16 + lr;
#pragma unroll
      for (int j = 0; j < 4; ++j)
#pragma unroll
        for (int r = 0; r < 4; ++r) {
          int n = n0 + wn + j * 16 + quad * 4 + r;
          out[(size_t)m * PP + n] = acc[i][j][r];
        }
    }
  }
}

// ---------------------------------------------------------------------------
// fw output + finalize x_rec. One thread per (n,p):
//   wv[e] = gate[n,e]*A[p,e];  denom = sum wv;  biasterm = sum wv*b3[e,p]
//   x_rec = (part0 + part1 + biasterm) / (denom + 1e-8);  fw = wv/denom'
// ---------------------------------------------------------------------------
__global__ void k_fw_final(const float* __restrict__ gate,
                           const ushort_t* __restrict__ Amat,   // [P][E] bf16
                           const ushort_t* __restrict__ b3,     // [E][P] bf16
                           const float* __restrict__ part,      // [S][N][P]
                           float* __restrict__ xrec,            // [N][P]
                           float* __restrict__ fw) {             // [N][P][E]
  __shared__ float sg[16];
  int n = blockIdx.y;
  int p = blockIdx.x * 256 + threadIdx.x;
  if (threadIdx.x < 16) sg[threadIdx.x] = gate[(size_t)n * EE + threadIdx.x];
  __syncthreads();
  uint4 a0 = *(const uint4*)(Amat + (size_t)p * EE);
  uint4 a1 = *(const uint4*)(Amat + (size_t)p * EE + 8);
  ushort_t av[16];
  *(uint4*)av = a0;
  *(uint4*)(av + 8) = a1;
  float wv[16];
  float s = 0.f, bias = 0.f;
#pragma unroll
  for (int e = 0; e < 16; ++e) {
    wv[e] = sg[e] * b2f(av[e]);
    s += wv[e];
    bias += wv[e] * b2f(b3[(size_t)e * PP + p]);
  }
  float inv = 1.f / (s + 1e-8f);
  size_t np = (size_t)n * PP + p;
  float num = part[np] + part[(size_t)NN * PP + np] + bias;
  xrec[np] = num * inv;
  float* dst = fw + np * EE;
#pragma unroll
  for (int e = 0; e < 16; ++e) wv[e] *= inv;
  *(float4*)(dst + 0)  = *(float4*)(wv + 0);
  *(float4*)(dst + 4)  = *(float4*)(wv + 4);
  *(float4*)(dst + 8)  = *(float4*)(wv + 8);
  *(float4*)(dst + 12) = *(float4*)(wv + 12);
}

// ---------------------------------------------------------------------------
extern "C" void kernel_launch(void* const* d_in, const int* in_sizes, int n_in,
                              void* d_out, int out_size, void* d_ws,
                              size_t ws_size, hipStream_t stream) {
  const void* z_r   = d_in[0];
  const void* W1_r  = d_in[1];
  const void* b1_r  = d_in[2];
  const void* W2_r  = d_in[3];
  const void* b2_r  = d_in[4];
  const void* W3_r  = d_in[5];
  const void* b3_r  = d_in[6];
  const void* Wg1_r = d_in[7];
  const void* bg1_r = d_in[8];
  const void* Wg2_r = d_in[9];
  const void* bg2_r = d_in[10];
  const void* A_r   = d_in[11];

  float* xrec = (float*)d_out;                       // [N][P] fp32
  float* fw   = (float*)d_out + (size_t)NN * PP;     // [N][P][E] fp32

  char* ws = (char*)d_ws;
  int* flag    = (int*)ws;             ws += 128;
  int* mapflag = (int*)ws;             ws += 128;
  float* gate = (float*)ws;            ws += (size_t)NN * EE * 4;
  ushort_t* zC   = (ushort_t*)ws;      ws += (size_t)NN * DD * 2;
  ushort_t* b1C  = (ushort_t*)ws;      ws += (size_t)EE * HH1 * 2;
  ushort_t* b2C  = (ushort_t*)ws;      ws += (size_t)EE * HH2 * 2;
  ushort_t* b3C  = (ushort_t*)ws;      ws += (size_t)EE * PP * 2;
  ushort_t* AC   = (ushort_t*)ws;      ws += (size_t)PP * EE * 2;
  ushort_t* W1t = (ushort_t*)ws;       ws += (size_t)EE * HH1 * DD * 2;
  ushort_t* W2t = (ushort_t*)ws;       ws += (size_t)EE * HH2 * HH1 * 2;
  ushort_t* W3big = (ushort_t*)ws;     ws += (size_t)PP * KBIG * 2;  // 32 MiB
  ushort_t* H2big = (ushort_t*)ws;     ws += (size_t)NN * KBIG * 2;  // 32 MiB
  ushort_t* h1  = (ushort_t*)ws;       ws += (size_t)EE * NN * HH1 * 2;  // 32 MiB
  // split-K partials alias h1 (dead after layer-2 GEMM); sizes match exactly:
  // SPLITS*NN*PP*4 = 32 MiB == EE*NN*HH1*2.
  float* partial = (float*)h1;

  // 1. dtype sniff + MFMA layout probe
  k_sniff<<<1, 256, 0, stream>>>((const unsigned int*)z_r, flag);
  k_probe<<<1, 64, 0, stream>>>(mapflag);

  // 2. canonicalize tensors feeding MFMA/epilogues to bf16
  auto cvt = [&](const void* src, ushort_t* dst, int n) {
    int blocks = (n / 8 + 255) / 256;
    if (blocks < 1) blocks = 1;
    k_convert<<<blocks, 256, 0, stream>>>(src, dst, n, flag);
  };
  cvt(z_r,  zC,  NN * DD);
  cvt(b1_r, b1C, EE * HH1);
  cvt(b2_r, b2C, EE * HH2);
  cvt(b3_r, b3C, EE * PP);
  cvt(A_r,  AC,  PP * EE);

  // 3. transpose+convert expert weights
  //    W1t [E][H1][D], W2t [E][H2][H1]; W3big [P][E*H2] with A[p,e] folded in.
  k_transpose_cvt<<<dim3(HH1 / 64, DD / 64, EE), 256, 0, stream>>>(
      W1_r, W1t, DD, HH1, DD, (long)HH1 * DD, nullptr, flag);
  k_transpose_cvt<<<dim3(HH2 / 64, HH1 / 64, EE), 256, 0, stream>>>(
      W2_r, W2t, HH1, HH2, HH1, (long)HH2 * HH1, nullptr, flag);
  k_transpose_cvt<<<dim3(PP / 64, HH2 / 64, EE), 256, 0, stream>>>(
      W3_r, W3big, HH2, PP, KBIG, (long)HH2, A_r, flag);

  // 4. gate (exact fp32 path from raw inputs) — must precede layer-2 GEMM
  k_gate<<<NN / 4, 256, 0, stream>>>(z_r, Wg1_r, bg1_r, Wg2_r, bg2_r, flag, gate);

  // 5. expert MLP layer 1 -> h1 [E][N][H1]
  k_gemm_bt_relu<<<dim3(HH1 / 128, NN / 128, EE), 256, 0, stream>>>(
      zC, W1t, b1C, h1, NN, DD, HH1,
      0, (long)HH1 * DD, HH1, (long)NN * HH1, nullptr, mapflag);
  //    layer 2 -> H2big [N][E*H2], gate-folded (e offset via c_stride_e)
  k_gemm_bt_relu<<<dim3(HH2 / 128, NN / 128, EE), 256, 0, stream>>>(
      h1, W2t, b2C, H2big, NN, HH1, KBIG,
      (long)NN * HH1, (long)HH2 * HH1, HH2, (long)HH2, gate, mapflag);

  // 6. combine numerator: one 2048x2048x8192 bf16 GEMM, split-K=2
  k_bigk<<<dim3(PP / 128, NN / 128, SPLITS), 256, 0, stream>>>(
      H2big, W3big, partial, mapflag);

  // 7. fw output + x_rec finalize (bias + denom rank-16 epilogue)
  k_fw_final<<<dim3(PP / 256, NN), 256, 0, stream>>>(
      gate, AC, b3C, partial, xrec, fw);
}